// Round 1
// baseline (1047.400 us; speedup 1.0000x reference)
//
#include <hip/hip_runtime.h>
#include <math.h>
#include <float.h>

// Problem constants (fixed by reference)
#define B_   8
#define F_   2048
#define N_   10000
#define J_   10
#define R_   20
#define H1_  200
#define H2_  100

// ---------------------------------------------------------------------------
// Kernel 1: fused full-F 1x1 conv.
// One block = 128 n-columns of one batch, ALL of F.
//   4 waves; wave w covers f in [w*512, w*512+512).
//   lane l owns n-pair (float2) n0+2l .. n0+2l+1  -> 8B/lane coalesced loads.
//   Weights w[j*F+f] are wave-uniform -> scalar loads (s_load), L2-resident.
//   4 partial sums per (n,j) reduced through 20 KB LDS, then emb stored.
// emb is only 3.2 MB total -> select reads it cache-hot. No partial planes.
// Grid: 79 n-chunks x 8 b = 632 blocks (~2.5/CU, well balanced).
// Tail chunk overlaps the previous one (identical recompute, benign
// double-write of bit-identical values) -> no divergence guards anywhere.
// ---------------------------------------------------------------------------
#define T1     256
#define NBLK   128
#define NB     ((N_ + NBLK - 1) / NBLK)     // 79
#define FSLICE (F_ / 4)                      // 512

__global__ __launch_bounds__(T1) void conv_kernel(
    const float* __restrict__ x, const float* __restrict__ w,
    float* __restrict__ emb)
{
    __shared__ float ls[4][J_][NBLK];        // 20 KB

    const int tid  = threadIdx.x;
    const int wid  = tid >> 6;               // wave id = f-slice id
    const int lane = tid & 63;
    const int b    = blockIdx.y;

    int n0 = blockIdx.x * NBLK;
    if (n0 > N_ - NBLK) n0 = N_ - NBLK;      // overlapped tail, no guards
    const int n  = n0 + 2 * lane;
    const int f0 = wid * FSLICE;

    const float* px = x + ((size_t)b * F_ + f0) * N_ + n;
    const float* pw = w + f0;                // wave-uniform -> s_load

    float2 acc[J_];
#pragma unroll
    for (int j = 0; j < J_; ++j) acc[j] = make_float2(0.f, 0.f);

#pragma unroll 4
    for (int f = 0; f < FSLICE; ++f) {
        const float2 xv = *(const float2*)px;
        px += N_;
#pragma unroll
        for (int j = 0; j < J_; ++j) {
            const float wj = pw[j * F_ + f];
            acc[j].x = fmaf(wj, xv.x, acc[j].x);
            acc[j].y = fmaf(wj, xv.y, acc[j].y);
        }
    }

#pragma unroll
    for (int j = 0; j < J_; ++j)
        *(float2*)&ls[wid][j][2 * lane] = acc[j];
    __syncthreads();

    // 1280 outputs, 5 per thread: sum 4 f-slices, store.
#pragma unroll
    for (int k = 0; k < 5; ++k) {
        const int idx = tid + k * 256;       // [0,1280)
        const int j   = idx >> 7;
        const int nl  = idx & (NBLK - 1);
        const float v = ls[0][j][nl] + ls[1][j][nl] + ls[2][j][nl] + ls[3][j][nl];
        emb[((size_t)b * J_ + j) * N_ + n0 + nl] = v;
    }
}

// ---------------------------------------------------------------------------
// Kernel 2: per (b,j) row of emb (40 KB, cache-hot): top-20 desc + bottom-20
// desc (+bias post-selection; uniform shift preserves order) -> mm
// ---------------------------------------------------------------------------
#define T2  256
#define LPT 20

__global__ __launch_bounds__(T2) void select_kernel(
    const float* __restrict__ emb, const float* __restrict__ conv_b,
    float* __restrict__ mm)
{
    __shared__ float ls_top[T2 * LPT];   // 20 KB
    __shared__ float ls_bot[T2 * LPT];   // 20 KB
    __shared__ float s_val[8];
    __shared__ int   s_tid[8];
    __shared__ float s_wv;
    __shared__ int   s_wt;

    const int tid = threadIdx.x;
    const int j   = blockIdx.x;
    const int b   = blockIdx.y;

    const float* row = emb + ((size_t)b * J_ + j) * N_;

    // per-thread sorted lists (top: descending, bot: ascending)
    float top[LPT], bot[LPT];
#pragma unroll
    for (int k = 0; k < LPT; ++k) { top[k] = -FLT_MAX; bot[k] = FLT_MAX; }

    for (int n = tid; n < N_; n += T2) {
        const float v = row[n];

        float tv = v;
#pragma unroll
        for (int k = 0; k < LPT; ++k) {
            if (tv > top[k]) { const float o = top[k]; top[k] = tv; tv = o; }
        }
        float bv = v;
#pragma unroll
        for (int k = 0; k < LPT; ++k) {
            if (bv < bot[k]) { const float o = bot[k]; bot[k] = bv; bv = o; }
        }
    }
#pragma unroll
    for (int k = 0; k < LPT; ++k) {
        ls_top[tid * LPT + k] = top[k];
        ls_bot[tid * LPT + k] = bot[k];
    }
    __syncthreads();

    const float bias = conv_b[j];
    float* out = mm + ((size_t)b * J_ + j) * (2 * R_);

    const int lane = tid & 63;
    const int wv_  = tid >> 6;
    int ht = 0, hb = 0;

    for (int r = 0; r < R_; ++r) {
        // ---- argmax round (256-way merge on list heads) ----
        {
            float v = ls_top[tid * LPT + ht];
            int   t = tid;
            for (int off = 32; off; off >>= 1) {
                const float vo = __shfl_down(v, off);
                const int   to = __shfl_down(t, off);
                if (vo > v) { v = vo; t = to; }
            }
            if (lane == 0) { s_val[wv_] = v; s_tid[wv_] = t; }
            __syncthreads();
            if (tid == 0) {
                float bv2 = s_val[0]; int bt = s_tid[0];
                for (int q = 1; q < T2 / 64; ++q)
                    if (s_val[q] > bv2) { bv2 = s_val[q]; bt = s_tid[q]; }
                s_wv = bv2; s_wt = bt;
            }
            __syncthreads();
            if (tid == s_wt) { ht++; out[r] = s_wv + bias; }
            __syncthreads();
        }
        // ---- argmin round ----
        {
            float v = ls_bot[tid * LPT + hb];
            int   t = tid;
            for (int off = 32; off; off >>= 1) {
                const float vo = __shfl_down(v, off);
                const int   to = __shfl_down(t, off);
                if (vo < v) { v = vo; t = to; }
            }
            if (lane == 0) { s_val[wv_] = v; s_tid[wv_] = t; }
            __syncthreads();
            if (tid == 0) {
                float bv2 = s_val[0]; int bt = s_tid[0];
                for (int q = 1; q < T2 / 64; ++q)
                    if (s_val[q] < bv2) { bv2 = s_val[q]; bt = s_tid[q]; }
                s_wv = bv2; s_wt = bt;
            }
            __syncthreads();
            // ascending r-th smallest -> position 39-r (bottom block stored descending)
            if (tid == s_wt) { hb++; out[2 * R_ - 1 - r] = s_wv + bias; }
            __syncthreads();
        }
    }
}

// ---------------------------------------------------------------------------
// Kernel 3: tiny MLP  [8,400] -> sigmoid(400x200) -> sigmoid(200x100) -> 100x2
// ---------------------------------------------------------------------------
__global__ __launch_bounds__(256) void mlp_kernel(
    const float* __restrict__ mm,
    const float* __restrict__ w1, const float* __restrict__ b1,
    const float* __restrict__ w2, const float* __restrict__ b2,
    const float* __restrict__ w3, const float* __restrict__ b3,
    float* __restrict__ out)
{
    __shared__ float h0[2 * R_ * J_];   // 400
    __shared__ float h1[H1_];           // 200
    __shared__ float h2[H2_];           // 100

    const int tid = threadIdx.x;
    const int b   = blockIdx.x;

    for (int i = tid; i < 2 * R_ * J_; i += 256) h0[i] = mm[b * 2 * R_ * J_ + i];
    __syncthreads();

    if (tid < H1_) {
        float acc = b1[tid];
#pragma unroll 4
        for (int i = 0; i < 2 * R_ * J_; ++i)
            acc = fmaf(h0[i], w1[i * H1_ + tid], acc);
        h1[tid] = 1.f / (1.f + expf(-acc));
    }
    __syncthreads();

    if (tid < H2_) {
        float acc = b2[tid];
#pragma unroll 4
        for (int i = 0; i < H1_; ++i)
            acc = fmaf(h1[i], w2[i * H2_ + tid], acc);
        h2[tid] = 1.f / (1.f + expf(-acc));
    }
    __syncthreads();

    if (tid < 2) {
        float acc = b3[tid];
        for (int i = 0; i < H2_; ++i)
            acc = fmaf(h2[i], w3[i * 2 + tid], acc);
        out[b * 2 + tid] = acc;
    }
}

// ---------------------------------------------------------------------------
extern "C" void kernel_launch(void* const* d_in, const int* in_sizes, int n_in,
                              void* d_out, int out_size, void* d_ws, size_t ws_size,
                              hipStream_t stream)
{
    const float* x      = (const float*)d_in[0];
    const float* conv_w = (const float*)d_in[1];
    const float* conv_b = (const float*)d_in[2];
    const float* w1     = (const float*)d_in[3];
    const float* b1     = (const float*)d_in[4];
    const float* w2     = (const float*)d_in[5];
    const float* b2     = (const float*)d_in[6];
    const float* w3     = (const float*)d_in[7];
    const float* b3     = (const float*)d_in[8];

    float* emb = (float*)d_ws;                       // B*J*N = 800,000 floats (3.2 MB)
    float* mm  = emb + (size_t)B_ * J_ * N_;         // B*J*2R = 3200 floats
    float* out = (float*)d_out;

    conv_kernel<<<dim3(NB, B_), T1, 0, stream>>>(x, conv_w, emb);
    select_kernel<<<dim3(J_, B_), T2, 0, stream>>>(emb, conv_b, mm);
    mlp_kernel<<<B_, 256, 0, stream>>>(mm, w1, b1, w2, b2, w3, b3, out);
}

// Round 2
// 940.241 us; speedup vs baseline: 1.1140x; 1.1140x over previous
//
#include <hip/hip_runtime.h>
#include <math.h>
#include <float.h>

// Problem constants (fixed by reference)
#define B_   8
#define F_   2048
#define N_   10000
#define J_   10
#define R_   20
#define H1_  200
#define H2_  100

// ---------------------------------------------------------------------------
// Kernel 1: fused full-F 1x1 conv.
// One block = 128 n-columns of one batch, ALL of F.
//   4 waves; wave w covers f in [w*512, w*512+512).
//   lane l owns n-pair (float2) n0+2l .. n0+2l+1  -> 8B/lane coalesced loads.
//   f0 goes through readfirstlane -> SGPR -> weight loads pw[j*F_+f] are
//   provably wave-uniform -> s_load (SMEM), NOT per-lane VMEM broadcasts.
//   (Round-1 lesson: tid-derived f0 made 10 weight loads/f go to the VMEM
//   pipe -> ~11x VMEM instruction inflation -> ~90 us regression.)
//   4 partial sums per (n,j) reduced through 20 KB LDS, then emb stored.
// emb is only 3.2 MB total -> select reads it cache-hot. No partial planes.
// Grid: 79 n-chunks x 8 b = 632 blocks (~2.5/CU, well balanced).
// Tail chunk overlaps the previous one (identical recompute, benign
// double-write of bit-identical values) -> no divergence guards anywhere.
// ---------------------------------------------------------------------------
#define T1     256
#define NBLK   128
#define NB     ((N_ + NBLK - 1) / NBLK)     // 79
#define FSLICE (F_ / 4)                      // 512

__global__ __launch_bounds__(T1) void conv_kernel(
    const float* __restrict__ x, const float* __restrict__ w,
    float* __restrict__ emb)
{
    __shared__ float ls[4][J_][NBLK];        // 20 KB

    const int tid  = threadIdx.x;
    const int wid  = tid >> 6;               // wave id = f-slice id
    const int lane = tid & 63;
    const int b    = blockIdx.y;

    int n0 = blockIdx.x * NBLK;
    if (n0 > N_ - NBLK) n0 = N_ - NBLK;      // overlapped tail, no guards
    const int n  = n0 + 2 * lane;

    // Force the f-slice base into an SGPR so weight addressing is provably
    // wave-uniform (s_load path).
    const int f0 = __builtin_amdgcn_readfirstlane(wid * FSLICE);

    const float* px = x + ((size_t)b * F_ + f0) * N_ + n;
    const float* pw = w + f0;                // SGPR base -> s_load

    float2 acc[J_];
#pragma unroll
    for (int j = 0; j < J_; ++j) acc[j] = make_float2(0.f, 0.f);

#pragma unroll 4
    for (int f = 0; f < FSLICE; ++f) {
        const float2 xv = *(const float2*)px;
        px += N_;
#pragma unroll
        for (int j = 0; j < J_; ++j) {
            const float wj = pw[j * F_ + f];
            acc[j].x = fmaf(wj, xv.x, acc[j].x);
            acc[j].y = fmaf(wj, xv.y, acc[j].y);
        }
    }

#pragma unroll
    for (int j = 0; j < J_; ++j)
        *(float2*)&ls[wid][j][2 * lane] = acc[j];
    __syncthreads();

    // 1280 outputs, 5 per thread: sum 4 f-slices, store.
#pragma unroll
    for (int k = 0; k < 5; ++k) {
        const int idx = tid + k * 256;       // [0,1280)
        const int j   = idx >> 7;
        const int nl  = idx & (NBLK - 1);
        const float v = ls[0][j][nl] + ls[1][j][nl] + ls[2][j][nl] + ls[3][j][nl];
        emb[((size_t)b * J_ + j) * N_ + n0 + nl] = v;
    }
}

// ---------------------------------------------------------------------------
// Kernel 2: per (b,j) row of emb (40 KB, cache-hot): top-20 desc + bottom-20
// desc (+bias post-selection; uniform shift preserves order) -> mm
// ---------------------------------------------------------------------------
#define T2  256
#define LPT 20

__global__ __launch_bounds__(T2) void select_kernel(
    const float* __restrict__ emb, const float* __restrict__ conv_b,
    float* __restrict__ mm)
{
    __shared__ float ls_top[T2 * LPT];   // 20 KB
    __shared__ float ls_bot[T2 * LPT];   // 20 KB
    __shared__ float s_val[8];
    __shared__ int   s_tid[8];
    __shared__ float s_wv;
    __shared__ int   s_wt;

    const int tid = threadIdx.x;
    const int j   = blockIdx.x;
    const int b   = blockIdx.y;

    const float* row = emb + ((size_t)b * J_ + j) * N_;

    // per-thread sorted lists (top: descending, bot: ascending)
    float top[LPT], bot[LPT];
#pragma unroll
    for (int k = 0; k < LPT; ++k) { top[k] = -FLT_MAX; bot[k] = FLT_MAX; }

    for (int n = tid; n < N_; n += T2) {
        const float v = row[n];

        float tv = v;
#pragma unroll
        for (int k = 0; k < LPT; ++k) {
            if (tv > top[k]) { const float o = top[k]; top[k] = tv; tv = o; }
        }
        float bv = v;
#pragma unroll
        for (int k = 0; k < LPT; ++k) {
            if (bv < bot[k]) { const float o = bot[k]; bot[k] = bv; bv = o; }
        }
    }
#pragma unroll
    for (int k = 0; k < LPT; ++k) {
        ls_top[tid * LPT + k] = top[k];
        ls_bot[tid * LPT + k] = bot[k];
    }
    __syncthreads();

    const float bias = conv_b[j];
    float* out = mm + ((size_t)b * J_ + j) * (2 * R_);

    const int lane = tid & 63;
    const int wv_  = tid >> 6;
    int ht = 0, hb = 0;

    for (int r = 0; r < R_; ++r) {
        // ---- argmax round (256-way merge on list heads) ----
        {
            float v = ls_top[tid * LPT + ht];
            int   t = tid;
            for (int off = 32; off; off >>= 1) {
                const float vo = __shfl_down(v, off);
                const int   to = __shfl_down(t, off);
                if (vo > v) { v = vo; t = to; }
            }
            if (lane == 0) { s_val[wv_] = v; s_tid[wv_] = t; }
            __syncthreads();
            if (tid == 0) {
                float bv2 = s_val[0]; int bt = s_tid[0];
                for (int q = 1; q < T2 / 64; ++q)
                    if (s_val[q] > bv2) { bv2 = s_val[q]; bt = s_tid[q]; }
                s_wv = bv2; s_wt = bt;
            }
            __syncthreads();
            if (tid == s_wt) { ht++; out[r] = s_wv + bias; }
            __syncthreads();
        }
        // ---- argmin round ----
        {
            float v = ls_bot[tid * LPT + hb];
            int   t = tid;
            for (int off = 32; off; off >>= 1) {
                const float vo = __shfl_down(v, off);
                const int   to = __shfl_down(t, off);
                if (vo < v) { v = vo; t = to; }
            }
            if (lane == 0) { s_val[wv_] = v; s_tid[wv_] = t; }
            __syncthreads();
            if (tid == 0) {
                float bv2 = s_val[0]; int bt = s_tid[0];
                for (int q = 1; q < T2 / 64; ++q)
                    if (s_val[q] < bv2) { bv2 = s_val[q]; bt = s_tid[q]; }
                s_wv = bv2; s_wt = bt;
            }
            __syncthreads();
            // ascending r-th smallest -> position 39-r (bottom block stored descending)
            if (tid == s_wt) { hb++; out[2 * R_ - 1 - r] = s_wv + bias; }
            __syncthreads();
        }
    }
}

// ---------------------------------------------------------------------------
// Kernel 3: tiny MLP  [8,400] -> sigmoid(400x200) -> sigmoid(200x100) -> 100x2
// ---------------------------------------------------------------------------
__global__ __launch_bounds__(256) void mlp_kernel(
    const float* __restrict__ mm,
    const float* __restrict__ w1, const float* __restrict__ b1,
    const float* __restrict__ w2, const float* __restrict__ b2,
    const float* __restrict__ w3, const float* __restrict__ b3,
    float* __restrict__ out)
{
    __shared__ float h0[2 * R_ * J_];   // 400
    __shared__ float h1[H1_];           // 200
    __shared__ float h2[H2_];           // 100

    const int tid = threadIdx.x;
    const int b   = blockIdx.x;

    for (int i = tid; i < 2 * R_ * J_; i += 256) h0[i] = mm[b * 2 * R_ * J_ + i];
    __syncthreads();

    if (tid < H1_) {
        float acc = b1[tid];
#pragma unroll 4
        for (int i = 0; i < 2 * R_ * J_; ++i)
            acc = fmaf(h0[i], w1[i * H1_ + tid], acc);
        h1[tid] = 1.f / (1.f + expf(-acc));
    }
    __syncthreads();

    if (tid < H2_) {
        float acc = b2[tid];
#pragma unroll 4
        for (int i = 0; i < H1_; ++i)
            acc = fmaf(h1[i], w2[i * H2_ + tid], acc);
        h2[tid] = 1.f / (1.f + expf(-acc));
    }
    __syncthreads();

    if (tid < 2) {
        float acc = b3[tid];
        for (int i = 0; i < H2_; ++i)
            acc = fmaf(h2[i], w3[i * 2 + tid], acc);
        out[b * 2 + tid] = acc;
    }
}

// ---------------------------------------------------------------------------
extern "C" void kernel_launch(void* const* d_in, const int* in_sizes, int n_in,
                              void* d_out, int out_size, void* d_ws, size_t ws_size,
                              hipStream_t stream)
{
    const float* x      = (const float*)d_in[0];
    const float* conv_w = (const float*)d_in[1];
    const float* conv_b = (const float*)d_in[2];
    const float* w1     = (const float*)d_in[3];
    const float* b1     = (const float*)d_in[4];
    const float* w2     = (const float*)d_in[5];
    const float* b2     = (const float*)d_in[6];
    const float* w3     = (const float*)d_in[7];
    const float* b3     = (const float*)d_in[8];

    float* emb = (float*)d_ws;                       // B*J*N = 800,000 floats (3.2 MB)
    float* mm  = emb + (size_t)B_ * J_ * N_;         // B*J*2R = 3200 floats
    float* out = (float*)d_out;

    conv_kernel<<<dim3(NB, B_), T1, 0, stream>>>(x, conv_w, emb);
    select_kernel<<<dim3(J_, B_), T2, 0, stream>>>(emb, conv_b, mm);
    mlp_kernel<<<B_, 256, 0, stream>>>(mm, w1, b1, w2, b2, w3, b3, out);
}